// Round 12
// baseline (186.714 us; speedup 1.0000x reference)
//
#include <hip/hip_runtime.h>
#include <math.h>

typedef unsigned short u16;
typedef unsigned long long u64;
typedef __bf16 bf16x8 __attribute__((ext_vector_type(8)));
typedef float f32x4 __attribute__((ext_vector_type(4)));
typedef unsigned short u16x8 __attribute__((ext_vector_type(8)));
typedef unsigned short u16x4 __attribute__((ext_vector_type(4)));

#define S_LEN 2048
#define BATCH 2
#define HID 512
#define NHEAD 8
#define DHEAD 64
#define DFF 2048
#define ROWS (BATCH * S_LEN)          // 4096
#define NQH (BATCH * NHEAD * S_LEN)   // 32768 q-head rows
#define NPART 4
#define KVSPAN (S_LEN / NPART)        // 512
#define QSCALE 0.18033688011112042f   // 0.125 * log2(e)

static __device__ __forceinline__ u16 f2bf(float f) {
  unsigned int u = __builtin_bit_cast(unsigned int, f);
  u += 0x7fffu + ((u >> 16) & 1u);
  return (u16)(u >> 16);
}
static __device__ __forceinline__ u16 f2bf_fast(float f) {
  return __builtin_bit_cast(u16, (__bf16)f);
}
static __device__ __forceinline__ float bf2f(u16 v) {
  return (float)__builtin_bit_cast(__bf16, v);
}

// async global->LDS, 16B per lane; lds dest is wave-uniform base (+lane*16 by HW).
static __device__ __forceinline__ void gl16(const void* g, void* l) {
  __builtin_amdgcn_global_load_lds(
      (const __attribute__((address_space(1))) void*)g,
      (__attribute__((address_space(3))) void*)l, 16, 0, 0);
}

// ---------------- prep megakernel: mask-pack | weight-convert | LN1 --------
__global__ __launch_bounds__(256) void prep_kernel(
    const void* __restrict__ mask, const float* __restrict__ x,
    const float* __restrict__ ln1g, const float* __restrict__ ln1b,
    const float* __restrict__ Wq, const float* __restrict__ Wk,
    const float* __restrict__ Wv, const float* __restrict__ Wo,
    const float* __restrict__ W1, const float* __restrict__ W2,
    u64* __restrict__ mpk, u16* __restrict__ wqkvT, u16* __restrict__ woT,
    u16* __restrict__ w1T, u16* __restrict__ w2T, u16* __restrict__ nx) {
  __shared__ u16 sT[64][80];
  int bid = blockIdx.x, tid = threadIdx.x;
  int wid = tid >> 6, lane = tid & 63;
  if (bid < 2048) {
    const unsigned int* m32 = (const unsigned int*)mask;
    unsigned int v0 = m32[lane];
    u64 bi = __ballot(v0 > 1u);
    u64 bf = __ballot(v0 != 0u && v0 != 0x3f800000u);
    int flag = (bi == 0ull) ? 1 : ((bf == 0ull) ? 2 : 0);
    int gw = (bid * 256 + tid) >> 6;
    const int nw = 8192;
    const int nwords = ROWS * (S_LEN / 64);  // 131072
    for (int wI = gw; wI < nwords; wI += nw) {
      size_t e = (size_t)wI * 64 + lane;
      bool bit;
      if (flag == 1) bit = ((const int*)mask)[e] != 0;
      else if (flag == 2) bit = ((const float*)mask)[e] != 0.f;
      else bit = ((const unsigned char*)mask)[e] != 0;
      u64 bb = __ballot(bit);
      if (lane == 0) {
        int row = wI >> 5, w = wI & 31;
        int b = row >> 11, qq = row & 2047;
        mpk[(((size_t)(b * 32 + (qq >> 6)) * 32 + w) << 6) + (qq & 63)] = bb;
      }
    }
  } else if (bid < 2816) {
    int id = bid - 2048;
    const float* W;
    u16* WT;
    int K, N, bx, by;
    if (id < 256) {
      int mat = id >> 6, sub = id & 63;
      bx = sub & 7; by = sub >> 3; K = 512; N = 512;
      W = (mat == 0) ? Wq : (mat == 1) ? Wk : (mat == 2) ? Wv : Wo;
      WT = (mat < 3) ? wqkvT + (size_t)mat * 512 * 512 : woT;
    } else if (id < 512) {
      int sub = id - 256;
      bx = sub & 31; by = sub >> 5; K = 512; N = 2048;
      W = W1; WT = w1T;
    } else {
      int sub = id - 512;
      bx = sub & 7; by = sub >> 3; K = 2048; N = 512;
      W = W2; WT = w2T;
    }
    int r = tid >> 2, c0 = (tid & 3) * 16;
    int k0 = by * 64, n0 = bx * 64;
    const float* src = W + (size_t)(k0 + r) * N + n0 + c0;
    u16x8 a, b;
#pragma unroll
    for (int j = 0; j < 8; ++j) a[j] = f2bf(src[j]);
#pragma unroll
    for (int j = 0; j < 8; ++j) b[j] = f2bf(src[8 + j]);
    *(u16x8*)&sT[r][c0] = a;
    *(u16x8*)&sT[r][c0 + 8] = b;
    __syncthreads();
    u16x8 o0, o1;
#pragma unroll
    for (int j = 0; j < 8; ++j) o0[j] = sT[c0 + j][r];
#pragma unroll
    for (int j = 0; j < 8; ++j) o1[j] = sT[c0 + 8 + j][r];
    u16* dst = WT + (size_t)(n0 + r) * K + k0 + c0;
    *(u16x8*)dst = o0;
    *(u16x8*)(dst + 8) = o1;
  } else {
    long row = (long)(bid - 2816) * 4 + wid;
    const float* xr = x + row * HID;
    float4 v0 = *(const float4*)(xr + lane * 8);
    float4 v1 = *(const float4*)(xr + lane * 8 + 4);
    float fr[8] = {v0.x, v0.y, v0.z, v0.w, v1.x, v1.y, v1.z, v1.w};
    float s = 0.f, q = 0.f;
#pragma unroll
    for (int j = 0; j < 8; ++j) { s += fr[j]; q += fr[j] * fr[j]; }
#pragma unroll
    for (int mby = 1; mby < 64; mby <<= 1) {
      s += __shfl_xor(s, mby);
      q += __shfl_xor(q, mby);
    }
    float mean = s * (1.f / HID);
    float var = q * (1.f / HID) - mean * mean;
    float rs = rsqrtf(var + 1e-5f);
    u16x8 ov;
#pragma unroll
    for (int j = 0; j < 8; ++j) {
      int c = lane * 8 + j;
      ov[j] = f2bf((fr[j] - mean) * rs * ln1g[c] + ln1b[c]);
    }
    *(u16x8*)(nx + row * HID + lane * 8) = ov;
  }
}

// ---------------- LayerNorm (f32 in, bf16 out), one wave per row ----------
__global__ __launch_bounds__(256) void ln_kernel(const float* __restrict__ x,
                                                 const float* __restrict__ g,
                                                 const float* __restrict__ b,
                                                 u16* __restrict__ o) {
  int wid = threadIdx.x >> 6, lane = threadIdx.x & 63;
  long row = (long)blockIdx.x * 4 + wid;
  const float* xr = x + row * HID;
  float4 v0 = *(const float4*)(xr + lane * 8);
  float4 v1 = *(const float4*)(xr + lane * 8 + 4);
  float fr[8] = {v0.x, v0.y, v0.z, v0.w, v1.x, v1.y, v1.z, v1.w};
  float s = 0.f, q = 0.f;
#pragma unroll
  for (int j = 0; j < 8; ++j) { s += fr[j]; q += fr[j] * fr[j]; }
#pragma unroll
  for (int mby = 1; mby < 64; mby <<= 1) {
    s += __shfl_xor(s, mby);
    q += __shfl_xor(q, mby);
  }
  float mean = s * (1.f / HID);
  float var = q * (1.f / HID) - mean * mean;
  float rs = rsqrtf(var + 1e-5f);
  u16x8 ov;
#pragma unroll
  for (int j = 0; j < 8; ++j) {
    int c = lane * 8 + j;
    ov[j] = f2bf((fr[j] - mean) * rs * g[c] + b[c]);
  }
  *(u16x8*)(o + row * HID + lane * 8) = ov;
}

// -------- bf16 MFMA GEMM (round-8 proven config): single-buffer, 2D grid ---
// EPI 0: fused QKV -> o1=q bf16 (pre-scaled), o2=khp, o3=vtp panels
// EPI 1: o1 f32 = resid + acc + bias
// EPI 2: o1 bf16 = gelu(acc + bias)
template <int BM, int BN, int EPI>
__global__ __launch_bounds__(256) void gemm3_kernel(
    const u16* __restrict__ A, const u16* __restrict__ BT,
    const float* __restrict__ bias, const float* __restrict__ bias2,
    const float* __restrict__ bias3, const float* __restrict__ resid,
    void* __restrict__ o1, void* __restrict__ o2, void* __restrict__ o3,
    int M, int N, int K) {
  constexpr int AM = BM / 32;
  constexpr int BNF = BN / 32;
  __shared__ alignas(16) u16 sA[BM * 64];
  __shared__ alignas(16) u16 sB[BN * 64];
  int tid = threadIdx.x, wid = tid >> 6, lane = tid & 63;
  int wm = wid >> 1, wn = wid & 1;
  int grp = lane >> 4, l16 = lane & 15;
  int m0 = blockIdx.y * BM, n0 = blockIdx.x * BN;
  f32x4 zz = {0.f, 0.f, 0.f, 0.f};
  f32x4 acc[AM][BNF];
#pragma unroll
  for (int i = 0; i < AM; ++i)
#pragma unroll
    for (int j = 0; j < BNF; ++j) acc[i][j] = zz;

  for (int k0 = 0; k0 < K; k0 += 64) {
#pragma unroll
    for (int i = 0; i < BM / 32; ++i) {
      int bb = i * 4096 + tid * 16;
      int row = bb >> 7;
      int cb = (bb & 127) ^ ((row & 7) << 4);
      gl16((const char*)A + ((size_t)(m0 + row) * K + k0) * 2 + cb,
           (char*)sA + i * 4096 + wid * 1024);
    }
#pragma unroll
    for (int i = 0; i < BN / 32; ++i) {
      int bb = i * 4096 + tid * 16;
      int row = bb >> 7;
      int cb = (bb & 127) ^ ((row & 7) << 4);
      gl16((const char*)BT + ((size_t)(n0 + row) * K + k0) * 2 + cb,
           (char*)sB + i * 4096 + wid * 1024);
    }
    __syncthreads();
    bf16x8 af[AM][2], bfr[BNF][2];
#pragma unroll
    for (int am = 0; am < AM; ++am) {
      int row = wm * (BM / 2) + am * 16 + l16;
#pragma unroll
      for (int kk = 0; kk < 2; ++kk)
        af[am][kk] = *(const bf16x8*)((const char*)sA + row * 128 +
                                      ((kk * 64 + grp * 16) ^ ((row & 7) << 4)));
    }
#pragma unroll
    for (int bn = 0; bn < BNF; ++bn) {
      int row = wn * (BN / 2) + bn * 16 + l16;
#pragma unroll
      for (int kk = 0; kk < 2; ++kk)
        bfr[bn][kk] = *(const bf16x8*)((const char*)sB + row * 128 +
                                       ((kk * 64 + grp * 16) ^ ((row & 7) << 4)));
    }
#pragma unroll
    for (int kk = 0; kk < 2; ++kk)
#pragma unroll
      for (int am = 0; am < AM; ++am)
#pragma unroll
        for (int bn = 0; bn < BNF; ++bn)
          acc[am][bn] = __builtin_amdgcn_mfma_f32_16x16x32_bf16(
              af[am][kk], bfr[bn][kk], acc[am][bn], 0, 0, 0);
    __syncthreads();
  }

#pragma unroll
  for (int am = 0; am < AM; ++am) {
#pragma unroll
    for (int bn = 0; bn < BNF; ++bn) {
      int gc = n0 + wn * (BN / 2) + bn * 16 + l16;
      long gr0 = m0 + wm * (BM / 2) + am * 16 + grp * 4;
      if constexpr (EPI == 0) {
        int bidx = (int)(gr0 >> 11), s0 = (int)(gr0 & 2047);
        if (gc < 512) {
          float bsv = bias[gc];
#pragma unroll
          for (int r = 0; r < 4; ++r)
            ((u16*)o1)[(size_t)(gr0 + r) * 512 + gc] =
                f2bf((acc[am][bn][r] + bsv) * QSCALE);
        } else if (gc < 1024) {
          int c = gc - 512, hh = c >> 6, d = c & 63;
          float bsv = bias2[c];
#pragma unroll
          for (int r = 0; r < 4; ++r)
            ((u16*)o2)[((size_t)(bidx * NHEAD + hh) * S_LEN + s0 + r) * 64 + d] =
                f2bf(acc[am][bn][r] + bsv);
        } else {
          int c = gc - 1024, hh = c >> 6, d = c & 63;
          float bsv = bias3[c];
          u16x4 pk;
#pragma unroll
          for (int r = 0; r < 4; ++r) pk[r] = f2bf(acc[am][bn][r] + bsv);
          *(u16x4*)((u16*)o3 +
                    (((size_t)(bidx * NHEAD + hh) * 32 + (s0 >> 6)) * 64 + d) * 64 +
                    (s0 & 63)) = pk;
        }
      } else if constexpr (EPI == 1) {
        float bsv = bias[gc];
        float* O = (float*)o1;
#pragma unroll
        for (int r = 0; r < 4; ++r) {
          size_t off = (size_t)(gr0 + r) * N + gc;
          O[off] = resid[off] + acc[am][bn][r] + bsv;
        }
      } else {
        float bsv = bias[gc];
        u16* O = (u16*)o1;
#pragma unroll
        for (int r = 0; r < 4; ++r) {
          float v = acc[am][bn][r] + bsv;
          O[(size_t)(gr0 + r) * N + gc] =
              f2bf(0.5f * v * (1.f + erff(v * 0.70710678118f)));
        }
      }
    }
  }
}

// -------- O-proj GEMM with FUSED 4-way combine -----------------------------
__global__ __launch_bounds__(256) void oproj_kernel(
    const u16* __restrict__ pbuf, const float2* __restrict__ mlb,
    const u16* __restrict__ BT, const float* __restrict__ bias,
    const float* __restrict__ resid, float* __restrict__ out) {
  __shared__ alignas(16) u16 sA[64 * 64];
  __shared__ alignas(16) u16 sB[64 * 64];
  int tid = threadIdx.x, wid = tid >> 6, lane = tid & 63;
  int wm = wid >> 1, wn = wid & 1;
  int grp = lane >> 4, l16 = lane & 15;
  int m0 = blockIdx.y * 64, n0 = blockIdx.x * 64;
  f32x4 zz = {0.f, 0.f, 0.f, 0.f};
  f32x4 acc[2][2] = {{zz, zz}, {zz, zz}};
  int ar = tid >> 2, ac = (tid & 3) * 16;
  int grow = m0 + ar;
  int bB = grow >> 11, q = grow & 2047;
  int rbase = bB * NHEAD * S_LEN + q;

  for (int k0 = 0; k0 < 512; k0 += 64) {
#pragma unroll
    for (int i = 0; i < 2; ++i) {
      int bb = i * 4096 + tid * 16;
      int row = bb >> 7;
      int cb = (bb & 127) ^ ((row & 7) << 4);
      gl16((const char*)BT + ((size_t)(n0 + row) * 512 + k0) * 2 + cb,
           (char*)sB + i * 4096 + wid * 1024);
    }
    int ridx = rbase + (k0 >> 6) * S_LEN;
    float2 ml[NPART];
    float M = -1e30f;
#pragma unroll
    for (int i = 0; i < NPART; ++i) {
      ml[i] = mlb[(size_t)i * NQH + ridx];
      M = fmaxf(M, ml[i].x);
    }
    float wgt[NPART], wsum = 0.f;
#pragma unroll
    for (int i = 0; i < NPART; ++i) {
      wgt[i] = __builtin_amdgcn_exp2f(ml[i].x - M);
      wsum += wgt[i] * ml[i].y;
    }
    float rden = 1.f / wsum;
#pragma unroll
    for (int i = 0; i < NPART; ++i) wgt[i] *= rden;
    float va[8] = {0, 0, 0, 0, 0, 0, 0, 0};
    float vb[8] = {0, 0, 0, 0, 0, 0, 0, 0};
#pragma unroll
    for (int i = 0; i < NPART; ++i) {
      const u16* pp = pbuf + ((size_t)i * NQH + ridx) * 64 + ac;
      u16x8 pa = *(const u16x8*)pp;
      u16x8 pb_ = *(const u16x8*)(pp + 8);
#pragma unroll
      for (int j = 0; j < 8; ++j) {
        va[j] += wgt[i] * bf2f(pa[j]);
        vb[j] += wgt[i] * bf2f(pb_[j]);
      }
    }
    u16x8 oa_, ob_;
#pragma unroll
    for (int j = 0; j < 8; ++j) {
      oa_[j] = f2bf_fast(va[j]);
      ob_[j] = f2bf_fast(vb[j]);
    }
    char* dst = (char*)sA + ar * 128;
    int xr_ = (ar & 7) << 4;
    *(u16x8*)(dst + ((ac * 2) ^ xr_)) = oa_;
    *(u16x8*)(dst + ((ac * 2 + 16) ^ xr_)) = ob_;
    __syncthreads();
    bf16x8 af[2][2], bfr[2][2];
#pragma unroll
    for (int am = 0; am < 2; ++am) {
      int row = wm * 32 + am * 16 + l16;
#pragma unroll
      for (int kk = 0; kk < 2; ++kk)
        af[am][kk] = *(const bf16x8*)((const char*)sA + row * 128 +
                                      ((kk * 64 + grp * 16) ^ ((row & 7) << 4)));
    }
#pragma unroll
    for (int bn = 0; bn < 2; ++bn) {
      int row = wn * 32 + bn * 16 + l16;
#pragma unroll
      for (int kk = 0; kk < 2; ++kk)
        bfr[bn][kk] = *(const bf16x8*)((const char*)sB + row * 128 +
                                       ((kk * 64 + grp * 16) ^ ((row & 7) << 4)));
    }
#pragma unroll
    for (int kk = 0; kk < 2; ++kk)
#pragma unroll
      for (int am = 0; am < 2; ++am)
#pragma unroll
        for (int bn = 0; bn < 2; ++bn)
          acc[am][bn] = __builtin_amdgcn_mfma_f32_16x16x32_bf16(
              af[am][kk], bfr[bn][kk], acc[am][bn], 0, 0, 0);
    __syncthreads();
  }

#pragma unroll
  for (int am = 0; am < 2; ++am) {
#pragma unroll
    for (int bn = 0; bn < 2; ++bn) {
      int gc = n0 + wn * 32 + bn * 16 + l16;
      long gr0 = m0 + wm * 32 + am * 16 + grp * 4;
      float bsv = bias[gc];
#pragma unroll
      for (int r = 0; r < 4; ++r) {
        size_t off = (size_t)(gr0 + r) * 512 + gc;
        out[off] = resid[off] + acc[am][bn][r] + bsv;
      }
    }
  }
}

// ---------------- flash attention: 4-way KV-split, SINGLE-buffered K/V -----
// 24 KB LDS -> 6 blocks/CU (was 40 KB -> 4). Two barriers/tile; cross-block
// TLP hides staging latency (round-10 lesson). Grid 2048 = 8/CU demand.
__global__ __launch_bounds__(256, 6) void attn_kernel(
    const u16* __restrict__ qg, const u16* __restrict__ khp,
    const u16* __restrict__ vtp, const u64* __restrict__ mpk,
    u16* __restrict__ pout, float2* __restrict__ mlb) {
  __shared__ alignas(16) char sKV[2][8192];  // [K/V][64x64 bf16 tile], single buf
  __shared__ alignas(16) u16 sP[4][16][64];  // per-wave, XOR-swizzled
  int tid = threadIdx.x;
  int wid = tid >> 6, lane = tid & 63;
  int grp = lane >> 4, l16 = lane & 15;
  int flat = blockIdx.x;
  int swz = (flat & 7) * 256 + (flat >> 3);  // 2048 blocks, 256-chunk per XCD
  int qblk = swz & 31, part = (swz >> 5) & 3, h = (swz >> 7) & 7, b = swz >> 10;
  int q0 = qblk * 64 + wid * 16;
  int q = q0 + l16;
  const u16* qp = qg + (size_t)(b * S_LEN + q) * HID + h * DHEAD + grp * 8;
  bf16x8 qf0 = *(const bf16x8*)qp;
  bf16x8 qf1 = *(const bf16x8*)(qp + 32);
  f32x4 zz = {0.f, 0.f, 0.f, 0.f};
  f32x4 oa[4] = {zz, zz, zz, zz};
  float mr = -1e30f, lr = 0.f;
  int hh = b * NHEAD + h;
  const char* kbase = (const char*)(khp + (size_t)hh * S_LEN * DHEAD);
  const char* vbase = (const char*)(vtp + (size_t)hh * S_LEN * DHEAD);
  const u64* mbase = mpk + (((size_t)(b * 32 + qblk) * 32) << 6) + wid * 16 + l16;
  int kvb = part * KVSPAN;

  auto stage = [&](int kv0) {
#pragma unroll
    for (int i = 0; i < 4; ++i) {
      int idx = wid * 4 + i;
      int sel = idx >> 3, j = idx & 7;
      int bb = j * 1024 + lane * 16;
      int row = bb >> 7;
      int cb = (bb & 127) ^ ((row & 7) << 4);
      const char* src =
          (sel ? vbase + ((size_t)(kv0 >> 6) << 13) : kbase + (size_t)kv0 * 128) +
          (bb & ~127) + cb;
      gl16(src, &sKV[sel][j * 1024]);
    }
  };

  char* sprow = (char*)sP + wid * 2048 + l16 * 128;
  int xw = (l16 & 7) << 4;

  for (int t = 0; t < KVSPAN / 64; ++t) {
    int kv0 = kvb + t * 64;
    stage(kv0);
    u64 mw = mbase[(size_t)(kv0 >> 6) << 6];  // overlaps staging
    __syncthreads();  // staging complete (vmcnt drained)
    const char* Kb = sKV[0];
    const char* Vb = sKV[1];
    bf16x8 kf[4][2];
#pragma unroll
    for (int nb = 0; nb < 4; ++nb) {
      int row = nb * 16 + l16;
      int x = (row & 7) << 4;
      kf[nb][0] = *(const bf16x8*)(Kb + row * 128 + ((grp * 16) ^ x));
      kf[nb][1] = *(const bf16x8*)(Kb + row * 128 + ((64 + grp * 16) ^ x));
    }
    bf16x8 vf[2][4];
#pragma unroll
    for (int ks = 0; ks < 2; ++ks)
#pragma unroll
      for (int db = 0; db < 4; ++db) {
        int row = db * 16 + l16;
        int x = (row & 7) << 4;
        vf[ks][db] =
            *(const bf16x8*)(Vb + row * 128 + ((ks * 64 + grp * 16) ^ x));
      }
    f32x4 st[4];
#pragma unroll
    for (int nb = 0; nb < 4; ++nb) {
      f32x4 s = zz;
      s = __builtin_amdgcn_mfma_f32_16x16x32_bf16(kf[nb][0], qf0, s, 0, 0, 0);
      s = __builtin_amdgcn_mfma_f32_16x16x32_bf16(kf[nb][1], qf1, s, 0, 0, 0);
      st[nb] = s;
    }
    // mask via u32 halves (bfe-shaped), then row max
    unsigned mlo = (unsigned)mw, mhi = (unsigned)(mw >> 32);
    float tmx = -1e30f;
#pragma unroll
    for (int nb = 0; nb < 4; ++nb) {
      unsigned msel = (nb < 2) ? mlo : mhi;
      int bb0 = (nb & 1) * 16 + grp * 4;
#pragma unroll
      for (int r = 0; r < 4; ++r) {
        float s = ((msel >> (bb0 + r)) & 1u) ? st[nb][r] : -1e9f;
        st[nb][r] = s;
        tmx = fmaxf(tmx, s);
      }
    }
    tmx = fmaxf(tmx, __shfl_xor(tmx, 16));
    tmx = fmaxf(tmx, __shfl_xor(tmx, 32));
    if (__any(tmx > mr + 4.f)) {  // defer-max: P bounded by 2^4
      float mnew = fmaxf(mr, tmx);
      float sc = __builtin_amdgcn_exp2f(mr - mnew);
      lr *= sc;
#pragma unroll
      for (int db = 0; db < 4; ++db)
#pragma unroll
        for (int r = 0; r < 4; ++r) oa[db][r] *= sc;
      mr = mnew;
    }
    float tsum = 0.f;
#pragma unroll
    for (int nb = 0; nb < 4; ++nb) {
      u16x4 pk;
#pragma unroll
      for (int r = 0; r < 4; ++r) {
        float p = __builtin_amdgcn_exp2f(st[nb][r] - mr);
        tsum += p;
        pk[r] = f2bf_fast(p);
      }
      *(u16x4*)(sprow + ((nb * 32 + grp * 8) ^ xw)) = pk;
    }
    tsum += __shfl_xor(tsum, 16);
    tsum += __shfl_xor(tsum, 32);
    lr += tsum;
    asm volatile("s_waitcnt lgkmcnt(0)" ::: "memory");
    __builtin_amdgcn_s_setprio(1);
#pragma unroll
    for (int ks = 0; ks < 2; ++ks) {
      bf16x8 pb = *(const bf16x8*)(sprow + ((ks * 64 + grp * 16) ^ xw));
#pragma unroll
      for (int db = 0; db < 4; ++db)
        oa[db] = __builtin_amdgcn_mfma_f32_16x16x32_bf16(vf[ks][db], pb, oa[db],
                                                         0, 0, 0);
    }
    __builtin_amdgcn_s_setprio(0);
    __syncthreads();  // all waves done with sKV before next stage overwrites
  }

  // epilogue: O^T -> [q][d] rows via per-wave LDS, coalesced nontemporal bursts
#pragma unroll
  for (int db = 0; db < 4; ++db) {
    u16x4 pk;
#pragma unroll
    for (int r = 0; r < 4; ++r) pk[r] = f2bf_fast(oa[db][r]);
    *(u16x4*)(sprow + ((db * 32 + grp * 8) ^ xw)) = pk;
  }
  asm volatile("s_waitcnt lgkmcnt(0)" ::: "memory");
  int rrow = lane >> 3, rcolb = (lane & 7) * 16;
  const char* spw = (const char*)sP + wid * 2048;
  u16x8 o0 = *(const u16x8*)(spw + rrow * 128 + (rcolb ^ ((rrow & 7) << 4)));
  u16x8 o1 =
      *(const u16x8*)(spw + (8 + rrow) * 128 + (rcolb ^ ((rrow & 7) << 4)));
  int ridx0 = hh * S_LEN + q0;
  u16* pp = pout + ((size_t)part * NQH + ridx0) * 64;
  __builtin_nontemporal_store(o0, (u16x8*)(pp + lane * 8));
  __builtin_nontemporal_store(o1, (u16x8*)(pp + 512 + lane * 8));
  if (grp == 0)
    mlb[(size_t)part * NQH + ridx0 + l16] = make_float2(mr, lr);
}

// ---------------- launch ----------------
extern "C" void kernel_launch(void* const* d_in, const int* in_sizes, int n_in,
                              void* d_out, int out_size, void* d_ws,
                              size_t ws_size, hipStream_t stream) {
  const float* x = (const float*)d_in[0];
  const void* mask = d_in[1];
  const float* ln1g = (const float*)d_in[2];
  const float* ln1b = (const float*)d_in[3];
  const float* ln2g = (const float*)d_in[4];
  const float* ln2b = (const float*)d_in[5];
  const float* Wq = (const float*)d_in[6];
  const float* bq = (const float*)d_in[7];
  const float* Wk = (const float*)d_in[8];
  const float* bk = (const float*)d_in[9];
  const float* Wv = (const float*)d_in[10];
  const float* bvp = (const float*)d_in[11];
  const float* Wo = (const float*)d_in[12];
  const float* bo = (const float*)d_in[13];
  const float* W1 = (const float*)d_in[14];
  const float* b1 = (const float*)d_in[15];
  const float* W2 = (const float*)d_in[16];
  const float* b2 = (const float*)d_in[17];

  char* w = (char*)d_ws;
  char* base = w + 256;
  // layout (peak ~42MB):
  //  0      mpk   1M (transposed pack)
  //  1M     mlb   1M (4 parts x 32768 x float2)
  //  2M     weights 6.3M (ends 8M)
  //  8M     nx    4M    (-> nx2 after attn)
  //  12M    qb    4M    \__ -> x2 f32 8M after attn
  //  16M    khp   4M    /
  //  20M    vtp   4M
  //  24M    p     16.8M (-> hb after O-proj)
  u64* mpk = (u64*)base;
  float2* mlb = (float2*)(base + 1048576);
  u16* wqkvT = (u16*)(base + 2097152);   // 1536 x 512
  u16* woT = wqkvT + 1536 * 512;         // 512 x 512
  u16* w1T = woT + 512 * 512;            // 2048 x 512
  u16* w2T = w1T + 2048 * 512;           // 512 x 2048
  u16* nx = (u16*)(base + 8388608);
  u16* nx2 = nx;
  u16* qb = (u16*)(base + 12582912);
  float* x2 = (float*)(base + 12582912);
  u16* khp = (u16*)(base + 16777216);
  u16* vtp = (u16*)(base + 20971520);
  u16* pbuf = (u16*)(base + 25165824);   // NPART x 32768 x 64 bf16 = 16.8M
  u16* hb = (u16*)(base + 25165824);

  prep_kernel<<<3840, 256, 0, stream>>>(mask, x, ln1g, ln1b, Wq, Wk, Wv, Wo,
                                        W1, W2, mpk, wqkvT, woT, w1T, w2T, nx);
  gemm3_kernel<128, 64, 0><<<dim3(24, 32), 256, 0, stream>>>(
      nx, wqkvT, bq, bk, bvp, nullptr, qb, khp, vtp, ROWS, 1536, HID);
  attn_kernel<<<2048, 256, 0, stream>>>(qb, khp, vtp, mpk, pbuf, mlb);
  oproj_kernel<<<dim3(8, 64), 256, 0, stream>>>(pbuf, mlb, woT, bo, x, x2);
  ln_kernel<<<1024, 256, 0, stream>>>(x2, ln2g, ln2b, nx2);
  gemm3_kernel<128, 64, 2><<<dim3(32, 32), 256, 0, stream>>>(
      nx2, w1T, b1, nullptr, nullptr, nullptr, hb, nullptr, nullptr, ROWS, DFF,
      HID);
  gemm3_kernel<64, 64, 1><<<dim3(8, 64), 256, 0, stream>>>(
      hb, w2T, b2, nullptr, nullptr, x2, d_out, nullptr, nullptr, ROWS, 512,
      DFF);
}

// Round 13
// 132.142 us; speedup vs baseline: 1.4130x; 1.4130x over previous
//
#include <hip/hip_runtime.h>
#include <math.h>

typedef unsigned short u16;
typedef unsigned long long u64;
typedef __bf16 bf16x8 __attribute__((ext_vector_type(8)));
typedef float f32x4 __attribute__((ext_vector_type(4)));
typedef unsigned short u16x8 __attribute__((ext_vector_type(8)));
typedef unsigned short u16x4 __attribute__((ext_vector_type(4)));

#define S_LEN 2048
#define BATCH 2
#define HID 512
#define NHEAD 8
#define DHEAD 64
#define DFF 2048
#define ROWS (BATCH * S_LEN)          // 4096
#define NQH (BATCH * NHEAD * S_LEN)   // 32768 q-head rows
#define NPART 2
#define KVSPAN (S_LEN / NPART)        // 1024
#define QSCALE 0.18033688011112042f   // 0.125 * log2(e)

static __device__ __forceinline__ u16 f2bf(float f) {
  unsigned int u = __builtin_bit_cast(unsigned int, f);
  u += 0x7fffu + ((u >> 16) & 1u);
  return (u16)(u >> 16);
}
static __device__ __forceinline__ u16 f2bf_fast(float f) {
  return __builtin_bit_cast(u16, (__bf16)f);
}
static __device__ __forceinline__ float bf2f(u16 v) {
  return (float)__builtin_bit_cast(__bf16, v);
}

// async global->LDS, 16B per lane; lds dest is wave-uniform base (+lane*16 by HW).
static __device__ __forceinline__ void gl16(const void* g, void* l) {
  __builtin_amdgcn_global_load_lds(
      (const __attribute__((address_space(1))) void*)g,
      (__attribute__((address_space(3))) void*)l, 16, 0, 0);
}

// ---------------- prep megakernel: mask-pack | weight-convert | LN1 --------
__global__ __launch_bounds__(256) void prep_kernel(
    const void* __restrict__ mask, const float* __restrict__ x,
    const float* __restrict__ ln1g, const float* __restrict__ ln1b,
    const float* __restrict__ Wq, const float* __restrict__ Wk,
    const float* __restrict__ Wv, const float* __restrict__ Wo,
    const float* __restrict__ W1, const float* __restrict__ W2,
    u64* __restrict__ mpk, u16* __restrict__ wqkvT, u16* __restrict__ woT,
    u16* __restrict__ w1T, u16* __restrict__ w2T, u16* __restrict__ nx) {
  __shared__ u16 sT[64][80];
  int bid = blockIdx.x, tid = threadIdx.x;
  int wid = tid >> 6, lane = tid & 63;
  if (bid < 2048) {
    const unsigned int* m32 = (const unsigned int*)mask;
    unsigned int v0 = m32[lane];
    u64 bi = __ballot(v0 > 1u);
    u64 bf = __ballot(v0 != 0u && v0 != 0x3f800000u);
    int flag = (bi == 0ull) ? 1 : ((bf == 0ull) ? 2 : 0);
    int gw = (bid * 256 + tid) >> 6;
    const int nw = 8192;
    const int nwords = ROWS * (S_LEN / 64);  // 131072
    for (int wI = gw; wI < nwords; wI += nw) {
      size_t e = (size_t)wI * 64 + lane;
      bool bit;
      if (flag == 1) bit = ((const int*)mask)[e] != 0;
      else if (flag == 2) bit = ((const float*)mask)[e] != 0.f;
      else bit = ((const unsigned char*)mask)[e] != 0;
      u64 bb = __ballot(bit);
      if (lane == 0) {
        int row = wI >> 5, w = wI & 31;
        int b = row >> 11, qq = row & 2047;
        mpk[(((size_t)(b * 32 + (qq >> 6)) * 32 + w) << 6) + (qq & 63)] = bb;
      }
    }
  } else if (bid < 2816) {
    int id = bid - 2048;
    const float* W;
    u16* WT;
    int K, N, bx, by;
    if (id < 256) {
      int mat = id >> 6, sub = id & 63;
      bx = sub & 7; by = sub >> 3; K = 512; N = 512;
      W = (mat == 0) ? Wq : (mat == 1) ? Wk : (mat == 2) ? Wv : Wo;
      WT = (mat < 3) ? wqkvT + (size_t)mat * 512 * 512 : woT;
    } else if (id < 512) {
      int sub = id - 256;
      bx = sub & 31; by = sub >> 5; K = 512; N = 2048;
      W = W1; WT = w1T;
    } else {
      int sub = id - 512;
      bx = sub & 7; by = sub >> 3; K = 2048; N = 512;
      W = W2; WT = w2T;
    }
    int r = tid >> 2, c0 = (tid & 3) * 16;
    int k0 = by * 64, n0 = bx * 64;
    const float* src = W + (size_t)(k0 + r) * N + n0 + c0;
    u16x8 a, b;
#pragma unroll
    for (int j = 0; j < 8; ++j) a[j] = f2bf(src[j]);
#pragma unroll
    for (int j = 0; j < 8; ++j) b[j] = f2bf(src[8 + j]);
    *(u16x8*)&sT[r][c0] = a;
    *(u16x8*)&sT[r][c0 + 8] = b;
    __syncthreads();
    u16x8 o0, o1;
#pragma unroll
    for (int j = 0; j < 8; ++j) o0[j] = sT[c0 + j][r];
#pragma unroll
    for (int j = 0; j < 8; ++j) o1[j] = sT[c0 + 8 + j][r];
    u16* dst = WT + (size_t)(n0 + r) * K + k0 + c0;
    *(u16x8*)dst = o0;
    *(u16x8*)(dst + 8) = o1;
  } else {
    long row = (long)(bid - 2816) * 4 + wid;
    const float* xr = x + row * HID;
    float4 v0 = *(const float4*)(xr + lane * 8);
    float4 v1 = *(const float4*)(xr + lane * 8 + 4);
    float fr[8] = {v0.x, v0.y, v0.z, v0.w, v1.x, v1.y, v1.z, v1.w};
    float s = 0.f, q = 0.f;
#pragma unroll
    for (int j = 0; j < 8; ++j) { s += fr[j]; q += fr[j] * fr[j]; }
#pragma unroll
    for (int mby = 1; mby < 64; mby <<= 1) {
      s += __shfl_xor(s, mby);
      q += __shfl_xor(q, mby);
    }
    float mean = s * (1.f / HID);
    float var = q * (1.f / HID) - mean * mean;
    float rs = rsqrtf(var + 1e-5f);
    u16x8 ov;
#pragma unroll
    for (int j = 0; j < 8; ++j) {
      int c = lane * 8 + j;
      ov[j] = f2bf((fr[j] - mean) * rs * ln1g[c] + ln1b[c]);
    }
    *(u16x8*)(nx + row * HID + lane * 8) = ov;
  }
}

// ---------------- LayerNorm (f32 in, bf16 out), one wave per row ----------
__global__ __launch_bounds__(256) void ln_kernel(const float* __restrict__ x,
                                                 const float* __restrict__ g,
                                                 const float* __restrict__ b,
                                                 u16* __restrict__ o) {
  int wid = threadIdx.x >> 6, lane = threadIdx.x & 63;
  long row = (long)blockIdx.x * 4 + wid;
  const float* xr = x + row * HID;
  float4 v0 = *(const float4*)(xr + lane * 8);
  float4 v1 = *(const float4*)(xr + lane * 8 + 4);
  float fr[8] = {v0.x, v0.y, v0.z, v0.w, v1.x, v1.y, v1.z, v1.w};
  float s = 0.f, q = 0.f;
#pragma unroll
  for (int j = 0; j < 8; ++j) { s += fr[j]; q += fr[j] * fr[j]; }
#pragma unroll
  for (int mby = 1; mby < 64; mby <<= 1) {
    s += __shfl_xor(s, mby);
    q += __shfl_xor(q, mby);
  }
  float mean = s * (1.f / HID);
  float var = q * (1.f / HID) - mean * mean;
  float rs = rsqrtf(var + 1e-5f);
  u16x8 ov;
#pragma unroll
  for (int j = 0; j < 8; ++j) {
    int c = lane * 8 + j;
    ov[j] = f2bf((fr[j] - mean) * rs * g[c] + b[c]);
  }
  *(u16x8*)(o + row * HID + lane * 8) = ov;
}

// -------- bf16 MFMA GEMM: C = A[MxK] * BT[NxK]^T, BK=64, tile BMxBN --------
// EPI 0: fused QKV -> o1=q bf16 [r][512] (pre-scaled), o2=khp [b,h][s][64],
//        o3=vtp [b,h][s/64][d][64] panels
// EPI 1: o1 f32 = resid + acc + bias
// EPI 2: o1 bf16 = gelu(acc + bias)
template <int BM, int BN, int EPI>
__global__ __launch_bounds__(256) void gemm3_kernel(
    const u16* __restrict__ A, const u16* __restrict__ BT,
    const float* __restrict__ bias, const float* __restrict__ bias2,
    const float* __restrict__ bias3, const float* __restrict__ resid,
    void* __restrict__ o1, void* __restrict__ o2, void* __restrict__ o3,
    int M, int N, int K) {
  constexpr int AM = BM / 32;
  constexpr int BNF = BN / 32;
  __shared__ alignas(16) u16 sA[BM * 64];
  __shared__ alignas(16) u16 sB[BN * 64];
  int tid = threadIdx.x, wid = tid >> 6, lane = tid & 63;
  int wm = wid >> 1, wn = wid & 1;
  int grp = lane >> 4, l16 = lane & 15;
  int m0 = blockIdx.y * BM, n0 = blockIdx.x * BN;
  f32x4 zz = {0.f, 0.f, 0.f, 0.f};
  f32x4 acc[AM][BNF];
#pragma unroll
  for (int i = 0; i < AM; ++i)
#pragma unroll
    for (int j = 0; j < BNF; ++j) acc[i][j] = zz;

  for (int k0 = 0; k0 < K; k0 += 64) {
#pragma unroll
    for (int i = 0; i < BM / 32; ++i) {
      int bb = i * 4096 + tid * 16;
      int row = bb >> 7;
      int cb = (bb & 127) ^ ((row & 7) << 4);
      gl16((const char*)A + ((size_t)(m0 + row) * K + k0) * 2 + cb,
           (char*)sA + i * 4096 + wid * 1024);
    }
#pragma unroll
    for (int i = 0; i < BN / 32; ++i) {
      int bb = i * 4096 + tid * 16;
      int row = bb >> 7;
      int cb = (bb & 127) ^ ((row & 7) << 4);
      gl16((const char*)BT + ((size_t)(n0 + row) * K + k0) * 2 + cb,
           (char*)sB + i * 4096 + wid * 1024);
    }
    __syncthreads();
    bf16x8 af[AM][2], bfr[BNF][2];
#pragma unroll
    for (int am = 0; am < AM; ++am) {
      int row = wm * (BM / 2) + am * 16 + l16;
#pragma unroll
      for (int kk = 0; kk < 2; ++kk)
        af[am][kk] = *(const bf16x8*)((const char*)sA + row * 128 +
                                      ((kk * 64 + grp * 16) ^ ((row & 7) << 4)));
    }
#pragma unroll
    for (int bn = 0; bn < BNF; ++bn) {
      int row = wn * (BN / 2) + bn * 16 + l16;
#pragma unroll
      for (int kk = 0; kk < 2; ++kk)
        bfr[bn][kk] = *(const bf16x8*)((const char*)sB + row * 128 +
                                       ((kk * 64 + grp * 16) ^ ((row & 7) << 4)));
    }
#pragma unroll
    for (int kk = 0; kk < 2; ++kk)
#pragma unroll
      for (int am = 0; am < AM; ++am)
#pragma unroll
        for (int bn = 0; bn < BNF; ++bn)
          acc[am][bn] = __builtin_amdgcn_mfma_f32_16x16x32_bf16(
              af[am][kk], bfr[bn][kk], acc[am][bn], 0, 0, 0);
    __syncthreads();
  }

#pragma unroll
  for (int am = 0; am < AM; ++am) {
#pragma unroll
    for (int bn = 0; bn < BNF; ++bn) {
      int gc = n0 + wn * (BN / 2) + bn * 16 + l16;
      long gr0 = m0 + wm * (BM / 2) + am * 16 + grp * 4;
      if constexpr (EPI == 0) {
        int bidx = (int)(gr0 >> 11), s0 = (int)(gr0 & 2047);
        if (gc < 512) {
          float bsv = bias[gc];
#pragma unroll
          for (int r = 0; r < 4; ++r)
            ((u16*)o1)[(size_t)(gr0 + r) * 512 + gc] =
                f2bf((acc[am][bn][r] + bsv) * QSCALE);
        } else if (gc < 1024) {
          int c = gc - 512, hh = c >> 6, d = c & 63;
          float bsv = bias2[c];
#pragma unroll
          for (int r = 0; r < 4; ++r)
            ((u16*)o2)[((size_t)(bidx * NHEAD + hh) * S_LEN + s0 + r) * 64 + d] =
                f2bf(acc[am][bn][r] + bsv);
        } else {
          int c = gc - 1024, hh = c >> 6, d = c & 63;
          float bsv = bias3[c];
          u16x4 pk;
#pragma unroll
          for (int r = 0; r < 4; ++r) pk[r] = f2bf(acc[am][bn][r] + bsv);
          *(u16x4*)((u16*)o3 +
                    (((size_t)(bidx * NHEAD + hh) * 32 + (s0 >> 6)) * 64 + d) * 64 +
                    (s0 & 63)) = pk;
        }
      } else if constexpr (EPI == 1) {
        float bsv = bias[gc];
        float* O = (float*)o1;
#pragma unroll
        for (int r = 0; r < 4; ++r) {
          size_t off = (size_t)(gr0 + r) * N + gc;
          O[off] = resid[off] + acc[am][bn][r] + bsv;
        }
      } else {
        float bsv = bias[gc];
        u16* O = (u16*)o1;
#pragma unroll
        for (int r = 0; r < 4; ++r) {
          float v = acc[am][bn][r] + bsv;
          O[(size_t)(gr0 + r) * N + gc] =
              f2bf(0.5f * v * (1.f + erff(v * 0.70710678118f)));
        }
      }
    }
  }
}

// -------- O-proj GEMM with FUSED combine: x2 = resid + (merge(p0,p1)) @ Wo --
__global__ __launch_bounds__(256) void oproj_kernel(
    const u16* __restrict__ pbuf, const float2* __restrict__ mlb,
    const u16* __restrict__ BT, const float* __restrict__ bias,
    const float* __restrict__ resid, float* __restrict__ out) {
  __shared__ alignas(16) u16 sA[64 * 64];
  __shared__ alignas(16) u16 sB[64 * 64];
  int tid = threadIdx.x, wid = tid >> 6, lane = tid & 63;
  int wm = wid >> 1, wn = wid & 1;
  int grp = lane >> 4, l16 = lane & 15;
  int m0 = blockIdx.y * 64, n0 = blockIdx.x * 64;
  f32x4 zz = {0.f, 0.f, 0.f, 0.f};
  f32x4 acc[2][2] = {{zz, zz}, {zz, zz}};
  int ar = tid >> 2, ac = (tid & 3) * 16;
  int grow = m0 + ar;
  int bB = grow >> 11, q = grow & 2047;
  int rbase = bB * NHEAD * S_LEN + q;

  for (int k0 = 0; k0 < 512; k0 += 64) {
#pragma unroll
    for (int i = 0; i < 2; ++i) {
      int bb = i * 4096 + tid * 16;
      int row = bb >> 7;
      int cb = (bb & 127) ^ ((row & 7) << 4);
      gl16((const char*)BT + ((size_t)(n0 + row) * 512 + k0) * 2 + cb,
           (char*)sB + i * 4096 + wid * 1024);
    }
    int ridx = rbase + (k0 >> 6) * S_LEN;
    float2 ml0 = mlb[ridx], ml1 = mlb[NQH + ridx];
    float M = fmaxf(ml0.x, ml1.x);
    float w0 = __builtin_amdgcn_exp2f(ml0.x - M);
    float w1 = __builtin_amdgcn_exp2f(ml1.x - M);
    float rden = 1.f / (w0 * ml0.y + w1 * ml1.y);
    w0 *= rden; w1 *= rden;
    u16x8 p0a = *(const u16x8*)(pbuf + (size_t)ridx * 64 + ac);
    u16x8 p0b = *(const u16x8*)(pbuf + (size_t)ridx * 64 + ac + 8);
    u16x8 p1a = *(const u16x8*)(pbuf + ((size_t)NQH + ridx) * 64 + ac);
    u16x8 p1b = *(const u16x8*)(pbuf + ((size_t)NQH + ridx) * 64 + ac + 8);
    u16x8 oa_, ob_;
#pragma unroll
    for (int j = 0; j < 8; ++j) {
      oa_[j] = f2bf_fast(w0 * bf2f(p0a[j]) + w1 * bf2f(p1a[j]));
      ob_[j] = f2bf_fast(w0 * bf2f(p0b[j]) + w1 * bf2f(p1b[j]));
    }
    char* dst = (char*)sA + ar * 128;
    int xr_ = (ar & 7) << 4;
    *(u16x8*)(dst + ((ac * 2) ^ xr_)) = oa_;
    *(u16x8*)(dst + ((ac * 2 + 16) ^ xr_)) = ob_;
    __syncthreads();
    bf16x8 af[2][2], bfr[2][2];
#pragma unroll
    for (int am = 0; am < 2; ++am) {
      int row = wm * 32 + am * 16 + l16;
#pragma unroll
      for (int kk = 0; kk < 2; ++kk)
        af[am][kk] = *(const bf16x8*)((const char*)sA + row * 128 +
                                      ((kk * 64 + grp * 16) ^ ((row & 7) << 4)));
    }
#pragma unroll
    for (int bn = 0; bn < 2; ++bn) {
      int row = wn * 32 + bn * 16 + l16;
#pragma unroll
      for (int kk = 0; kk < 2; ++kk)
        bfr[bn][kk] = *(const bf16x8*)((const char*)sB + row * 128 +
                                       ((kk * 64 + grp * 16) ^ ((row & 7) << 4)));
    }
#pragma unroll
    for (int kk = 0; kk < 2; ++kk)
#pragma unroll
      for (int am = 0; am < 2; ++am)
#pragma unroll
        for (int bn = 0; bn < 2; ++bn)
          acc[am][bn] = __builtin_amdgcn_mfma_f32_16x16x32_bf16(
              af[am][kk], bfr[bn][kk], acc[am][bn], 0, 0, 0);
    __syncthreads();
  }

#pragma unroll
  for (int am = 0; am < 2; ++am) {
#pragma unroll
    for (int bn = 0; bn < 2; ++bn) {
      int gc = n0 + wn * 32 + bn * 16 + l16;
      long gr0 = m0 + wm * 32 + am * 16 + grp * 4;
      float bsv = bias[gc];
#pragma unroll
      for (int r = 0; r < 4; ++r) {
        size_t off = (size_t)(gr0 + r) * 512 + gc;
        out[off] = resid[off] + acc[am][bn][r] + bsv;
      }
    }
  }
}

// ---------------- flash attention: LDS-staged K/V, 2-way KV-split ----------
__global__ __launch_bounds__(256, 4) void attn_kernel(
    const u16* __restrict__ qg, const u16* __restrict__ khp,
    const u16* __restrict__ vtp, const u64* __restrict__ mpk,
    u16* __restrict__ pout, float2* __restrict__ mlb) {
  __shared__ alignas(16) char sKV[2][2][8192];  // [buf][K/V][64x64 bf16 tile]
  __shared__ alignas(16) u16 sP[4][16][64];     // per-wave, XOR-swizzled
  int tid = threadIdx.x;
  int wid = tid >> 6, lane = tid & 63;
  int grp = lane >> 4, l16 = lane & 15;
  int flat = blockIdx.x;
  int swz = (flat & 7) * 128 + (flat >> 3);
  int qblk = swz & 31, part = (swz >> 5) & 1, h = (swz >> 6) & 7, b = swz >> 9;
  int q0 = qblk * 64 + wid * 16;
  int q = q0 + l16;
  const u16* qp = qg + (size_t)(b * S_LEN + q) * HID + h * DHEAD + grp * 8;
  bf16x8 qf0 = *(const bf16x8*)qp;
  bf16x8 qf1 = *(const bf16x8*)(qp + 32);
  f32x4 zz = {0.f, 0.f, 0.f, 0.f};
  f32x4 oa[4] = {zz, zz, zz, zz};
  float mr = -1e30f, lr = 0.f;
  int hh = b * NHEAD + h;
  const char* kbase = (const char*)(khp + (size_t)hh * S_LEN * DHEAD);
  const char* vbase = (const char*)(vtp + (size_t)hh * S_LEN * DHEAD);
  const u64* mbase = mpk + (((size_t)(b * 32 + qblk) * 32) << 6) + wid * 16 + l16;
  int kvb = part * KVSPAN;

  auto stage = [&](int bsel, int kv0) {
#pragma unroll
    for (int i = 0; i < 4; ++i) {
      int idx = wid * 4 + i;
      int sel = idx >> 3, j = idx & 7;
      int bb = j * 1024 + lane * 16;
      int row = bb >> 7;
      int cb = (bb & 127) ^ ((row & 7) << 4);
      const char* src =
          (sel ? vbase + ((size_t)(kv0 >> 6) << 13) : kbase + (size_t)kv0 * 128) +
          (bb & ~127) + cb;
      gl16(src, &sKV[bsel][sel][j * 1024]);
    }
  };

  stage(0, kvb);
  u64 mw = mbase[(size_t)(kvb >> 6) << 6];
  __syncthreads();
  int buf = 0;
  char* sprow = (char*)sP + wid * 2048 + l16 * 128;
  int xw = (l16 & 7) << 4;

  for (int t = 0; t < KVSPAN / 64; ++t, buf ^= 1) {
    int kv0 = kvb + t * 64;
    if (t + 1 < KVSPAN / 64) stage(buf ^ 1, kv0 + 64);
    u64 mw_next = mbase[(size_t)((kv0 >> 6) + 1) << 6];
    const char* Kb = sKV[buf][0];
    const char* Vb = sKV[buf][1];
    bf16x8 kf[4][2];
#pragma unroll
    for (int nb = 0; nb < 4; ++nb) {
      int row = nb * 16 + l16;
      int x = (row & 7) << 4;
      kf[nb][0] = *(const bf16x8*)(Kb + row * 128 + ((grp * 16) ^ x));
      kf[nb][1] = *(const bf16x8*)(Kb + row * 128 + ((64 + grp * 16) ^ x));
    }
    bf16x8 vf[2][4];
#pragma unroll
    for (int ks = 0; ks < 2; ++ks)
#pragma unroll
      for (int db = 0; db < 4; ++db) {
        int row = db * 16 + l16;
        int x = (row & 7) << 4;
        vf[ks][db] =
            *(const bf16x8*)(Vb + row * 128 + ((ks * 64 + grp * 16) ^ x));
      }
    f32x4 st[4];
#pragma unroll
    for (int nb = 0; nb < 4; ++nb) {
      f32x4 s = zz;
      s = __builtin_amdgcn_mfma_f32_16x16x32_bf16(kf[nb][0], qf0, s, 0, 0, 0);
      s = __builtin_amdgcn_mfma_f32_16x16x32_bf16(kf[nb][1], qf1, s, 0, 0, 0);
      st[nb] = s;
    }
    float tmx = -1e30f;
#pragma unroll
    for (int nb = 0; nb < 4; ++nb)
#pragma unroll
      for (int r = 0; r < 4; ++r) {
        int kbit = nb * 16 + grp * 4 + r;
        float s = ((mw >> kbit) & 1ull) ? st[nb][r] : -1e9f;
        st[nb][r] = s;
        tmx = fmaxf(tmx, s);
      }
    mw = mw_next;
    tmx = fmaxf(tmx, __shfl_xor(tmx, 16));
    tmx = fmaxf(tmx, __shfl_xor(tmx, 32));
    if (__any(tmx > mr + 4.f)) {  // defer-max: P bounded by 2^4
      float mnew = fmaxf(mr, tmx);
      float sc = __builtin_amdgcn_exp2f(mr - mnew);
      lr *= sc;
#pragma unroll
      for (int db = 0; db < 4; ++db)
#pragma unroll
        for (int r = 0; r < 4; ++r) oa[db][r] *= sc;
      mr = mnew;
    }
    float tsum = 0.f;
#pragma unroll
    for (int nb = 0; nb < 4; ++nb) {
      u16x4 pk;
#pragma unroll
      for (int r = 0; r < 4; ++r) {
        float p = __builtin_amdgcn_exp2f(st[nb][r] - mr);
        tsum += p;
        pk[r] = f2bf_fast(p);
      }
      *(u16x4*)(sprow + ((nb * 32 + grp * 8) ^ xw)) = pk;
    }
    tsum += __shfl_xor(tsum, 16);
    tsum += __shfl_xor(tsum, 32);
    lr += tsum;
    asm volatile("s_waitcnt lgkmcnt(0)" ::: "memory");
    __builtin_amdgcn_s_setprio(1);
#pragma unroll
    for (int ks = 0; ks < 2; ++ks) {
      bf16x8 pb = *(const bf16x8*)(sprow + ((ks * 64 + grp * 16) ^ xw));
#pragma unroll
      for (int db = 0; db < 4; ++db)
        oa[db] = __builtin_amdgcn_mfma_f32_16x16x32_bf16(vf[ks][db], pb, oa[db],
                                                         0, 0, 0);
    }
    __builtin_amdgcn_s_setprio(0);
    __syncthreads();  // drains vmcnt (next tile staged) + lgkm; all waves done
  }

  // epilogue: O^T -> [q][d] rows via per-wave LDS, coalesced nontemporal bursts
#pragma unroll
  for (int db = 0; db < 4; ++db) {
    u16x4 pk;
#pragma unroll
    for (int r = 0; r < 4; ++r) pk[r] = f2bf_fast(oa[db][r]);
    *(u16x4*)(sprow + ((db * 32 + grp * 8) ^ xw)) = pk;
  }
  asm volatile("s_waitcnt lgkmcnt(0)" ::: "memory");
  int rrow = lane >> 3, rcolb = (lane & 7) * 16;
  const char* spw = (const char*)sP + wid * 2048;
  u16x8 o0 = *(const u16x8*)(spw + rrow * 128 + (rcolb ^ ((rrow & 7) << 4)));
  u16x8 o1 =
      *(const u16x8*)(spw + (8 + rrow) * 128 + (rcolb ^ ((rrow & 7) << 4)));
  int ridx0 = hh * S_LEN + q0;
  u16* pp = pout + ((size_t)part * NQH + ridx0) * 64;
  __builtin_nontemporal_store(o0, (u16x8*)(pp + lane * 8));
  __builtin_nontemporal_store(o1, (u16x8*)(pp + 512 + lane * 8));
  if (grp == 0)
    mlb[(size_t)part * NQH + ridx0 + l16] = make_float2(mr, lr);
}

// ---------------- launch ----------------
extern "C" void kernel_launch(void* const* d_in, const int* in_sizes, int n_in,
                              void* d_out, int out_size, void* d_ws,
                              size_t ws_size, hipStream_t stream) {
  const float* x = (const float*)d_in[0];
  const void* mask = d_in[1];
  const float* ln1g = (const float*)d_in[2];
  const float* ln1b = (const float*)d_in[3];
  const float* ln2g = (const float*)d_in[4];
  const float* ln2b = (const float*)d_in[5];
  const float* Wq = (const float*)d_in[6];
  const float* bq = (const float*)d_in[7];
  const float* Wk = (const float*)d_in[8];
  const float* bk = (const float*)d_in[9];
  const float* Wv = (const float*)d_in[10];
  const float* bvp = (const float*)d_in[11];
  const float* Wo = (const float*)d_in[12];
  const float* bo = (const float*)d_in[13];
  const float* W1 = (const float*)d_in[14];
  const float* b1 = (const float*)d_in[15];
  const float* W2 = (const float*)d_in[16];
  const float* b2 = (const float*)d_in[17];

  char* w = (char*)d_ws;
  char* base = w + 256;
  u64* mpk = (u64*)base;
  float2* mlb = (float2*)(base + 1048576);
  u16* wqkvT = (u16*)(base + 2097152);   // 1536 x 512
  u16* woT = wqkvT + 1536 * 512;         // 512 x 512
  u16* w1T = woT + 512 * 512;            // 2048 x 512
  u16* w2T = w1T + 2048 * 512;           // 512 x 2048
  u16* nx = (u16*)(base + 8388608);
  u16* nx2 = nx;
  u16* qb = (u16*)(base + 12582912);
  float* x2 = (float*)(base + 12582912);
  u16* khp = (u16*)(base + 16777216);
  u16* vtp = (u16*)(base + 20971520);
  u16* pbuf = (u16*)(base + 25165824);   // NPART x 32768 x 64 bf16 = 8.4M
  u16* hb = (u16*)(base + 25165824);

  prep_kernel<<<3840, 256, 0, stream>>>(mask, x, ln1g, ln1b, Wq, Wk, Wv, Wo,
                                        W1, W2, mpk, wqkvT, woT, w1T, w2T, nx);
  gemm3_kernel<128, 64, 0><<<dim3(24, 32), 256, 0, stream>>>(
      nx, wqkvT, bq, bk, bvp, nullptr, qb, khp, vtp, ROWS, 1536, HID);
  attn_kernel<<<1024, 256, 0, stream>>>(qb, khp, vtp, mpk, pbuf, mlb);
  oproj_kernel<<<dim3(8, 64), 256, 0, stream>>>(pbuf, mlb, woT, bo, x, x2);
  ln_kernel<<<1024, 256, 0, stream>>>(x2, ln2g, ln2b, nx2);
  gemm3_kernel<128, 64, 2><<<dim3(32, 32), 256, 0, stream>>>(
      nx2, w1T, b1, nullptr, nullptr, nullptr, hb, nullptr, nullptr, ROWS, DFF,
      HID);
  gemm3_kernel<64, 64, 1><<<dim3(8, 64), 256, 0, stream>>>(
      hb, w2T, b2, nullptr, nullptr, x2, d_out, nullptr, nullptr, ROWS, 512,
      DFF);
}